// Round 13
// baseline (1460.248 us; speedup 1.0000x reference)
//
#include <hip/hip_runtime.h>

#define BS 256
#define BSB 512      // block size for binhist/bin
#define BSF 1024     // block size for bucket-streaming kernels
#define GPN 16       // lanes per node in fallback gather props
#define NBLKB 1024   // blocks in binning pass
#define BSH 8        // nodes per bucket = 256
#define NPB (1 << BSH)
#define SMAX 400     // max buckets supported by staged k_bin (N <= 102400)

static __device__ __forceinline__ float relu_(float v) { return fmaxf(v, 0.0f); }

// ======================= bucketed edge binning (r7-proven) =======================

__global__ void k_binhist(const int* __restrict__ dst, int* __restrict__ bcnt,
                          int E, int chunk, int nbuck) {
  __shared__ int h[1024];
  int b = blockIdx.x, t = threadIdx.x;
  for (int i = t; i < nbuck; i += BSB) h[i] = 0;
  __syncthreads();
  int beg = b * chunk, end = min(E, beg + chunk);
  for (int e = beg + t; e < end; e += BSB) atomicAdd(&h[dst[e] >> BSH], 1);
  __syncthreads();
  for (int i = t; i < nbuck; i += BSB) bcnt[(size_t)i * NBLKB + b] = h[i];
}

__global__ void k_bucketscan(int* __restrict__ bcnt, int* __restrict__ btot) {
  __shared__ int sh[BS];
  int bkt = blockIdx.x, t = threadIdx.x;
  size_t base = (size_t)bkt * NBLKB;
  int c[4], s = 0;
#pragma unroll
  for (int j = 0; j < 4; ++j) { c[j] = bcnt[base + t * 4 + j]; s += c[j]; }
  sh[t] = s; __syncthreads();
  for (int off = 1; off < BS; off <<= 1) {
    int add = (t >= off) ? sh[t - off] : 0; __syncthreads();
    sh[t] += add; __syncthreads();
  }
  int run = sh[t] - s;
#pragma unroll
  for (int j = 0; j < 4; ++j) { bcnt[base + t * 4 + j] = run; run += c[j]; }
  if (t == BS - 1) btot[bkt] = run;
}

__global__ void k_basescan(const int* __restrict__ btot, int* __restrict__ bbase, int nbuck) {
  __shared__ int sh[BS];
  int t = threadIdx.x;
  int run = 0;
  for (int c = 0; c < nbuck; c += BS) {
    int i = c + t;
    int v = (i < nbuck) ? btot[i] : 0;
    sh[t] = v; __syncthreads();
    for (int off = 1; off < BS; off <<= 1) {
      int add = (t >= off) ? sh[t - off] : 0; __syncthreads();
      sh[t] += add; __syncthreads();
    }
    if (i < nbuck) bbase[i] = run + sh[t] - v;
    run += sh[BS - 1];
    __syncthreads();
  }
}

// bin edges into bucket-contiguous bed[] = {(d_local<<17)|src, |attr|}
__global__ void k_bin(const int* __restrict__ src, const int* __restrict__ dst,
                      const float* __restrict__ attr, const int* __restrict__ bcnt,
                      const int* __restrict__ bbase, int2* __restrict__ bed,
                      int E, int chunk, int nbuck) {
  __shared__ int2 stage[SMAX][9];   // 72B rows: bank=(bkt*18+slot*2)%32
  __shared__ int  fc[SMAX];
  __shared__ int  cur[SMAX];
  int b = blockIdx.x, t = threadIdx.x;
  for (int i = t; i < nbuck; i += BSB) {
    cur[i] = bbase[i] + bcnt[(size_t)i * NBLKB + b];
    fc[i] = 0;
  }
  __syncthreads();
  int beg = b * chunk, end = min(E, beg + chunk);
  for (int base = beg; base < end; base += BSB) {
    int e = base + t;
    if (e < end) {
      int d = dst[e];
      int bkt = d >> BSH;
      int2 rec = make_int2((int)(((unsigned)(d & (NPB - 1)) << 17) | (unsigned)src[e]),
                           __float_as_int(fabsf(attr[e])));
      int slot = atomicAdd(&fc[bkt], 1);
      if (slot < 8) stage[bkt][slot] = rec;
      else { int gp = atomicAdd(&cur[bkt], 1); bed[gp] = rec; }  // rare spill
    }
    __syncthreads();
    for (int i = t; i < nbuck; i += BSB) {
      int c = fc[i]; if (c > 8) c = 8;
      if (c == 8) {
        int gp = cur[i]; cur[i] = gp + 8;
#pragma unroll
        for (int j = 0; j < 8; ++j) bed[gp + j] = stage[i][j];
        fc[i] = 0;
      }
    }
    __syncthreads();
  }
  for (int i = t; i < nbuck; i += BSB) {
    int c = fc[i]; if (c > 8) c = 8;
    if (c) {
      int gp = cur[i];
      for (int j = 0; j < c; ++j) bed[gp + j] = stage[i][j];
    }
  }
}

// per bucket: degree + dis + xhat (no rowptr/adj needed in bucket-streaming mode)
__global__ void kb_degdis(const int2* __restrict__ bed, const int* __restrict__ bbase,
                          const int* __restrict__ btot, const float* __restrict__ x,
                          float* __restrict__ dis, float* __restrict__ xhat, int N) {
  __shared__ float ld[NPB];
  int bkt = blockIdx.x, t = threadIdx.x;
  if (t < NPB) ld[t] = 0.f;
  __syncthreads();
  int beg = bbase[bkt], tot = btot[bkt];
  for (int i = t; i < tot; i += BSF) {
    int2 rec = bed[beg + i];
    atomicAdd(&ld[(unsigned)rec.x >> 17], __int_as_float(rec.y));
  }
  __syncthreads();
  if (t < NPB) {
    int n = (bkt << BSH) + t;
    if (n < N) {
      float dg = ld[t];
      float d = (dg > 0.f) ? (1.0f / sqrtf(dg)) : 0.f;
      dis[n] = d;
      xhat[n] = d * x[n];
    }
  }
}

// ======================= bucket-streaming u-space props =======================
// acc[dl] += w * uin[src]  (LDS float atomics), then per-node epilogue.

__global__ void kb_gp1_uh(const int2* __restrict__ bed, const int* __restrict__ bbase,
                          const int* __restrict__ btot, const float* __restrict__ uin,
                          const float* __restrict__ dis, float* __restrict__ hout,
                          float* __restrict__ uout, int N) {
  __shared__ float acc[NPB];
  int bkt = blockIdx.x, t = threadIdx.x;
  if (t < NPB) acc[t] = 0.f;
  __syncthreads();
  int beg = bbase[bkt], tot = btot[bkt];
  for (int i = t; i < tot; i += BSF) {
    int2 rec = bed[beg + i];
    unsigned u = (unsigned)rec.x;
    atomicAdd(&acc[u >> 17], __int_as_float(rec.y) * uin[u & 0x1FFFFu]);
  }
  __syncthreads();
  if (t < NPB) {
    int n = (bkt << BSH) + t;
    if (n < N) {
      float d = dis[n];
      float h = d * acc[t];
      hout[n] = h;
      uout[n] = d * h;
    }
  }
}

__global__ void kb_gp1_y(const int2* __restrict__ bed, const int* __restrict__ bbase,
                         const int* __restrict__ btot, const float* __restrict__ u2,
                         const float* __restrict__ x, const float* __restrict__ h1,
                         const float* __restrict__ h2, const float* __restrict__ dis,
                         const float* __restrict__ W1, const float* __restrict__ b1,
                         const float* __restrict__ W23, float* __restrict__ y,
                         float* __restrict__ Phat, int N) {
  __shared__ float acc[NPB];
  int bkt = blockIdx.x, t = threadIdx.x;
  if (t < NPB) acc[t] = 0.f;
  __syncthreads();
  int beg = bbase[bkt], tot = btot[bkt];
  for (int i = t; i < tot; i += BSF) {
    int2 rec = bed[beg + i];
    unsigned u = (unsigned)rec.x;
    atomicAdd(&acc[u >> 17], __int_as_float(rec.y) * u2[u & 0x1FFFFu]);
  }
  __syncthreads();
  if (t < NPB) {
    int n = (bkt << BSH) + t;
    if (n < N) {
      float d = dis[n];
      float xv = x[n], a = h1[n], b = h2[n], c = d * acc[t];
      float o[8];
#pragma unroll
      for (int j = 0; j < 8; ++j)
        o[j] = relu_(xv * W1[j] + a * W1[8 + j] + b * W1[16 + j] + c * W1[24 + j] + b1[j]);
      float4* op = (float4*)(y + (size_t)n * 8);
      op[0] = make_float4(o[0], o[1], o[2], o[3]);
      op[1] = make_float4(o[4], o[5], o[6], o[7]);
      float pv[8];
#pragma unroll
      for (int j = 0; j < 8; ++j) {
        float s = 0.0f;
#pragma unroll
        for (int i2 = 0; i2 < 8; ++i2) s += o[i2] * W23[i2 * 8 + j];
        pv[j] = d * s;
      }
      float4* pp = (float4*)(Phat + (size_t)n * 8);
      pp[0] = make_float4(pv[0], pv[1], pv[2], pv[3]);
      pp[1] = make_float4(pv[4], pv[5], pv[6], pv[7]);
    }
  }
}

// 8-dim streaming body: acc[NPB][9] padded (bank=(dl*9+j)%32 spreads all banks)
#define KB8_STREAM(UIN)                                                          \
  __shared__ float acc[NPB][9];                                                  \
  int bkt = blockIdx.x, t = threadIdx.x;                                         \
  for (int i = t; i < NPB * 9; i += BSF) ((float*)acc)[i] = 0.f;                 \
  __syncthreads();                                                               \
  int beg = bbase[bkt], tot = btot[bkt];                                         \
  for (int i = t; i < tot; i += BSF) {                                           \
    int2 rec = bed[beg + i];                                                     \
    unsigned u = (unsigned)rec.x;                                                \
    int dl = (int)(u >> 17), s = (int)(u & 0x1FFFFu);                            \
    float w = __int_as_float(rec.y);                                             \
    const float4* hp = (const float4*)((UIN) + (size_t)s * 8);                   \
    float4 a = hp[0], b = hp[1];                                                 \
    atomicAdd(&acc[dl][0], w * a.x); atomicAdd(&acc[dl][1], w * a.y);            \
    atomicAdd(&acc[dl][2], w * a.z); atomicAdd(&acc[dl][3], w * a.w);            \
    atomicAdd(&acc[dl][4], w * b.x); atomicAdd(&acc[dl][5], w * b.y);            \
    atomicAdd(&acc[dl][6], w * b.z); atomicAdd(&acc[dl][7], w * b.w);            \
  }                                                                              \
  __syncthreads();

__global__ void kb_gp8_u(const int2* __restrict__ bed, const int* __restrict__ bbase,
                         const int* __restrict__ btot, const float* __restrict__ uin,
                         const float* __restrict__ y, const float* __restrict__ W,
                         const float* __restrict__ dis, float* __restrict__ uout, int N) {
  KB8_STREAM(uin)
  if (t < NPB) {
    int n = (bkt << BSH) + t;
    if (n < N) {
      float d = dis[n];
      const float4* yp = (const float4*)(y + (size_t)n * 8);
      float4 u = yp[0], v = yp[1];
      float yi[8] = {u.x, u.y, u.z, u.w, v.x, v.y, v.z, v.w};
      float o[8];
#pragma unroll
      for (int j = 0; j < 8; ++j) {
        float s = 0.0f;
#pragma unroll
        for (int i2 = 0; i2 < 8; ++i2) s += yi[i2] * W[i2 * 8 + j];
        o[j] = d * (s + d * acc[t][j]);
      }
      float4* op = (float4*)(uout + (size_t)n * 8);
      op[0] = make_float4(o[0], o[1], o[2], o[3]);
      op[1] = make_float4(o[4], o[5], o[6], o[7]);
    }
  }
}

__global__ void kb_gp8_fin(const int2* __restrict__ bed, const int* __restrict__ bbase,
                           const int* __restrict__ btot, const float* __restrict__ uin,
                           const float* __restrict__ y, const float* __restrict__ W0,
                           const float* __restrict__ b2, const float* __restrict__ W3,
                           const float* __restrict__ dis, float* __restrict__ S3hat,
                           float* __restrict__ B2, float* __restrict__ B1,
                           float* __restrict__ B0, int N) {
  KB8_STREAM(uin)
  if (t < NPB) {
    int n = (bkt << BSH) + t;
    if (n < N) {
      float d = dis[n];
      const float4* yp = (const float4*)(y + (size_t)n * 8);
      float4 u = yp[0], v = yp[1];
      float yi[8] = {u.x, u.y, u.z, u.w, v.x, v.y, v.z, v.w};
      float z[8];
#pragma unroll
      for (int j = 0; j < 8; ++j) {
        float s = 0.0f;
#pragma unroll
        for (int i2 = 0; i2 < 8; ++i2) s += yi[i2] * W0[i2 * 8 + j];
        z[j] = relu_(s + d * acc[t][j] + b2[j]);
      }
      float tt[4];
#pragma unroll
      for (int i2 = 0; i2 < 4; ++i2) {
        float s = 0.0f;
#pragma unroll
        for (int j = 0; j < 8; ++j) s += z[j] * W3[i2 * 8 + j];
        tt[i2] = s;
      }
      B0[n] = tt[0]; B1[n] = tt[1]; B2[n] = tt[2];
      S3hat[n] = d * tt[3];
    }
  }
}

__global__ void kb_gp1_bu(const int2* __restrict__ bed, const int* __restrict__ bbase,
                          const int* __restrict__ btot, const float* __restrict__ uin,
                          const float* __restrict__ B, const float* __restrict__ dis,
                          float* __restrict__ uout, int N) {
  __shared__ float acc[NPB];
  int bkt = blockIdx.x, t = threadIdx.x;
  if (t < NPB) acc[t] = 0.f;
  __syncthreads();
  int beg = bbase[bkt], tot = btot[bkt];
  for (int i = t; i < tot; i += BSF) {
    int2 rec = bed[beg + i];
    unsigned u = (unsigned)rec.x;
    atomicAdd(&acc[u >> 17], __int_as_float(rec.y) * uin[u & 0x1FFFFu]);
  }
  __syncthreads();
  if (t < NPB) {
    int n = (bkt << BSH) + t;
    if (n < N) {
      float d = dis[n];
      uout[n] = d * (B[n] + d * acc[t]);
    }
  }
}

__global__ void kb_gp1_last(const int2* __restrict__ bed, const int* __restrict__ bbase,
                            const int* __restrict__ btot, const float* __restrict__ uin,
                            const float* __restrict__ B0, const float* __restrict__ b3,
                            const float* __restrict__ dis, float* __restrict__ r,
                            unsigned* __restrict__ keys, double* __restrict__ partials, int N) {
  __shared__ float acc[NPB];
  __shared__ double s1[BSF];
  __shared__ double s2[BSF];
  int bkt = blockIdx.x, t = threadIdx.x;
  if (t < NPB) acc[t] = 0.f;
  __syncthreads();
  int beg = bbase[bkt], tot = btot[bkt];
  for (int i = t; i < tot; i += BSF) {
    int2 rec = bed[beg + i];
    unsigned u = (unsigned)rec.x;
    atomicAdd(&acc[u >> 17], __int_as_float(rec.y) * uin[u & 0x1FFFFu]);
  }
  __syncthreads();
  double v = 0.0;
  if (t < NPB) {
    int n = (bkt << BSH) + t;
    if (n < N) {
      float d = dis[n];
      float rv = relu_(B0[n] + d * acc[t] + b3[0]);
      r[n] = rv;
      keys[n] = __float_as_uint(rv) | 0x80000000u;  // rv >= 0
      v = (double)rv;
    }
  }
  s1[t] = v;
  s2[t] = v * v;
  __syncthreads();
  for (int off = BSF / 2; off; off >>= 1) {
    if (t < off) { s1[t] += s1[t + off]; s2[t] += s2[t + off]; }
    __syncthreads();
  }
  if (t == 0) {
    partials[2 * (size_t)bkt]     = s1[0];
    partials[2 * (size_t)bkt + 1] = s2[0];
  }
}

// ======================= fallback CSR build + gather props (r7) =======================

__global__ void k_scanA(const int* __restrict__ cnt, int* __restrict__ bsum, int N) {
  __shared__ int sh[BS];
  int t = threadIdx.x;
  int base = blockIdx.x * 1024;
  int s = 0;
#pragma unroll
  for (int j = 0; j < 4; ++j) { int i = base + t * 4 + j; s += (i < N) ? cnt[i] : 0; }
  sh[t] = s; __syncthreads();
  for (int off = 128; off; off >>= 1) { if (t < off) sh[t] += sh[t + off]; __syncthreads(); }
  if (t == 0) bsum[blockIdx.x] = sh[0];
}

__global__ void k_scanB(int* __restrict__ bsum, int NB2) {
  __shared__ int sh[BS];
  int t = threadIdx.x;
  int v = (t < NB2) ? bsum[t] : 0;
  sh[t] = v; __syncthreads();
  for (int off = 1; off < BS; off <<= 1) {
    int add = (t >= off) ? sh[t - off] : 0; __syncthreads();
    sh[t] += add; __syncthreads();
  }
  if (t < NB2) bsum[t] = sh[t] - v;
}

__global__ void k_scanC(const int* __restrict__ cnt, const int* __restrict__ bsum,
                        int* __restrict__ rowptr, int* __restrict__ cursor, int N, int E) {
  __shared__ int sh[BS];
  int b = blockIdx.x, t = threadIdx.x;
  int base = b * 1024;
  int c[4]; int s = 0;
#pragma unroll
  for (int j = 0; j < 4; ++j) { int i = base + t * 4 + j; c[j] = (i < N) ? cnt[i] : 0; s += c[j]; }
  sh[t] = s; __syncthreads();
  for (int off = 1; off < BS; off <<= 1) {
    int add = (t >= off) ? sh[t - off] : 0; __syncthreads();
    sh[t] += add; __syncthreads();
  }
  int run = sh[t] - s + bsum[b];
#pragma unroll
  for (int j = 0; j < 4; ++j) {
    int i = base + t * 4 + j;
    if (i < N) { rowptr[i] = run; if (cursor) cursor[i] = run; run += c[j]; }
  }
  if (b == 0 && t == 0) rowptr[N] = E;
}

__global__ void k_count(const int* __restrict__ dst, int* __restrict__ cnt, int E) {
  int e = blockIdx.x * blockDim.x + threadIdx.x;
  if (e < E) atomicAdd(&cnt[dst[e]], 1);
}

__global__ void k_place(const int* __restrict__ src, const int* __restrict__ dst,
                        const float* __restrict__ attr, int* __restrict__ cursor,
                        int2* __restrict__ adj, int E) {
  int e = blockIdx.x * blockDim.x + threadIdx.x;
  if (e >= E) return;
  int d = dst[e];
  int pos = atomicAdd(&cursor[d], 1);
  adj[pos] = make_int2(src[e], __float_as_int(fabsf(attr[e])));
}

__global__ void k_degdis(const int* __restrict__ rowptr, const int2* __restrict__ adj,
                         const float* __restrict__ x, float* __restrict__ dis,
                         float* __restrict__ xhat, int N) {
  int g = (blockIdx.x * blockDim.x + threadIdx.x) / GPN;
  int l = threadIdx.x & (GPN - 1);
  if (g >= N) return;
  int beg = rowptr[g], end = rowptr[g + 1];
  float s = 0.0f;
  for (int e = beg + l; e < end; e += GPN) s += __int_as_float(adj[e].y);
#pragma unroll
  for (int off = 8; off; off >>= 1) s += __shfl_xor(s, off, GPN);
  if (l == 0) {
    float d = (s > 0.0f) ? (1.0f / sqrtf(s)) : 0.0f;
    dis[g] = d;
    xhat[g] = d * x[g];
  }
}

static __device__ __forceinline__ float edge_sum1(const int2* __restrict__ adj,
                                                  const float* __restrict__ uin,
                                                  int beg, int end, int l) {
  float acc0 = 0.0f, acc1 = 0.0f;
  int e = beg + l;
  int last = end - GPN;
  for (; e < last; e += 2 * GPN) {
    int2 s0 = adj[e], s1 = adj[e + GPN];
    acc0 += __int_as_float(s0.y) * uin[s0.x];
    acc1 += __int_as_float(s1.y) * uin[s1.x];
  }
  if (e < end) { int2 s0 = adj[e]; acc0 += __int_as_float(s0.y) * uin[s0.x]; }
  float acc = acc0 + acc1;
#pragma unroll
  for (int off = 8; off; off >>= 1) acc += __shfl_xor(acc, off, GPN);
  return acc;
}

__global__ void k_gp1_uh(const int* __restrict__ rowptr, const int2* __restrict__ adj,
                         const float* __restrict__ uin, const float* __restrict__ dis,
                         float* __restrict__ hout, float* __restrict__ uout, int N) {
  int g = (blockIdx.x * blockDim.x + threadIdx.x) / GPN;
  int l = threadIdx.x & (GPN - 1);
  if (g >= N) return;
  float acc = edge_sum1(adj, uin, rowptr[g], rowptr[g + 1], l);
  if (l == 0) {
    float d = dis[g];
    float h = d * acc;
    hout[g] = h;
    uout[g] = d * h;
  }
}

__global__ void k_gp1_y(const int* __restrict__ rowptr, const int2* __restrict__ adj,
                        const float* __restrict__ u2, const float* __restrict__ x,
                        const float* __restrict__ h1, const float* __restrict__ h2,
                        const float* __restrict__ dis, const float* __restrict__ W1,
                        const float* __restrict__ b1, const float* __restrict__ W23,
                        float* __restrict__ y, float* __restrict__ Phat, int N) {
  int g = (blockIdx.x * blockDim.x + threadIdx.x) / GPN;
  int l = threadIdx.x & (GPN - 1);
  if (g >= N) return;
  float acc = edge_sum1(adj, u2, rowptr[g], rowptr[g + 1], l);
  if (l == 0) {
    float d = dis[g];
    float xv = x[g], a = h1[g], b = h2[g], c = d * acc;
    float o[8];
#pragma unroll
    for (int j = 0; j < 8; ++j)
      o[j] = relu_(xv * W1[j] + a * W1[8 + j] + b * W1[16 + j] + c * W1[24 + j] + b1[j]);
    float4* op = (float4*)(y + (size_t)g * 8);
    op[0] = make_float4(o[0], o[1], o[2], o[3]);
    op[1] = make_float4(o[4], o[5], o[6], o[7]);
    float p[8];
#pragma unroll
    for (int j = 0; j < 8; ++j) {
      float s = 0.0f;
#pragma unroll
      for (int i = 0; i < 8; ++i) s += o[i] * W23[i * 8 + j];
      p[j] = d * s;
    }
    float4* pp = (float4*)(Phat + (size_t)g * 8);
    pp[0] = make_float4(p[0], p[1], p[2], p[3]);
    pp[1] = make_float4(p[4], p[5], p[6], p[7]);
  }
}

#define EDGE_SUM8(ADJ, UIN, BEG, END, L)                                        \
  float a0=0,a1=0,a2=0,a3=0,a4=0,a5=0,a6=0,a7=0;                                \
  {                                                                             \
    int e = (BEG) + (L);                                                        \
    int last = (END) - GPN;                                                     \
    for (; e < last; e += 2 * GPN) {                                            \
      int2 s0 = (ADJ)[e], s1 = (ADJ)[e + GPN];                                  \
      float w0 = __int_as_float(s0.y), w1 = __int_as_float(s1.y);               \
      const float4* p0 = (const float4*)((UIN) + (size_t)s0.x * 8);             \
      const float4* p1 = (const float4*)((UIN) + (size_t)s1.x * 8);             \
      float4 u0 = p0[0], v0 = p0[1], u1 = p1[0], v1 = p1[1];                    \
      a0 += w0*u0.x; a1 += w0*u0.y; a2 += w0*u0.z; a3 += w0*u0.w;               \
      a4 += w0*v0.x; a5 += w0*v0.y; a6 += w0*v0.z; a7 += w0*v0.w;               \
      a0 += w1*u1.x; a1 += w1*u1.y; a2 += w1*u1.z; a3 += w1*u1.w;               \
      a4 += w1*v1.x; a5 += w1*v1.y; a6 += w1*v1.z; a7 += w1*v1.w;               \
    }                                                                           \
    if (e < (END)) {                                                            \
      int2 s0 = (ADJ)[e];                                                       \
      float w0 = __int_as_float(s0.y);                                          \
      const float4* p0 = (const float4*)((UIN) + (size_t)s0.x * 8);             \
      float4 u0 = p0[0], v0 = p0[1];                                            \
      a0 += w0*u0.x; a1 += w0*u0.y; a2 += w0*u0.z; a3 += w0*u0.w;               \
      a4 += w0*v0.x; a5 += w0*v0.y; a6 += w0*v0.z; a7 += w0*v0.w;               \
    }                                                                           \
  }                                                                             \
  _Pragma("unroll")                                                             \
  for (int off = 8; off; off >>= 1) {                                           \
    a0 += __shfl_xor(a0, off, GPN); a1 += __shfl_xor(a1, off, GPN);             \
    a2 += __shfl_xor(a2, off, GPN); a3 += __shfl_xor(a3, off, GPN);             \
    a4 += __shfl_xor(a4, off, GPN); a5 += __shfl_xor(a5, off, GPN);             \
    a6 += __shfl_xor(a6, off, GPN); a7 += __shfl_xor(a7, off, GPN);             \
  }

__global__ void k_gp8_u(const int* __restrict__ rowptr, const int2* __restrict__ adj,
                        const float* __restrict__ uin, const float* __restrict__ y,
                        const float* __restrict__ W, const float* __restrict__ dis,
                        float* __restrict__ uout, int N) {
  int g = (blockIdx.x * blockDim.x + threadIdx.x) / GPN;
  int l = threadIdx.x & (GPN - 1);
  if (g >= N) return;
  int beg = rowptr[g], end = rowptr[g + 1];
  EDGE_SUM8(adj, uin, beg, end, l)
  if (l == 0) {
    float d = dis[g];
    const float4* yp = (const float4*)(y + (size_t)g * 8);
    float4 u = yp[0], v = yp[1];
    float yi[8] = {u.x, u.y, u.z, u.w, v.x, v.y, v.z, v.w};
    float acc[8] = {a0, a1, a2, a3, a4, a5, a6, a7};
    float o[8];
#pragma unroll
    for (int j = 0; j < 8; ++j) {
      float s = 0.0f;
#pragma unroll
      for (int i = 0; i < 8; ++i) s += yi[i] * W[i * 8 + j];
      o[j] = d * (s + d * acc[j]);
    }
    float4* op = (float4*)(uout + (size_t)g * 8);
    op[0] = make_float4(o[0], o[1], o[2], o[3]);
    op[1] = make_float4(o[4], o[5], o[6], o[7]);
  }
}

__global__ void k_gp8_fin(const int* __restrict__ rowptr, const int2* __restrict__ adj,
                          const float* __restrict__ uin, const float* __restrict__ y,
                          const float* __restrict__ W0, const float* __restrict__ b2,
                          const float* __restrict__ W3, const float* __restrict__ dis,
                          float* __restrict__ S3hat, float* __restrict__ B2,
                          float* __restrict__ B1, float* __restrict__ B0, int N) {
  int g = (blockIdx.x * blockDim.x + threadIdx.x) / GPN;
  int l = threadIdx.x & (GPN - 1);
  if (g >= N) return;
  int beg = rowptr[g], end = rowptr[g + 1];
  EDGE_SUM8(adj, uin, beg, end, l)
  if (l == 0) {
    float d = dis[g];
    const float4* yp = (const float4*)(y + (size_t)g * 8);
    float4 u = yp[0], v = yp[1];
    float yi[8] = {u.x, u.y, u.z, u.w, v.x, v.y, v.z, v.w};
    float acc[8] = {a0, a1, a2, a3, a4, a5, a6, a7};
    float z[8];
#pragma unroll
    for (int j = 0; j < 8; ++j) {
      float s = 0.0f;
#pragma unroll
      for (int i = 0; i < 8; ++i) s += yi[i] * W0[i * 8 + j];
      z[j] = relu_(s + d * acc[j] + b2[j]);
    }
    float tt[4];
#pragma unroll
    for (int i = 0; i < 4; ++i) {
      float s = 0.0f;
#pragma unroll
      for (int j = 0; j < 8; ++j) s += z[j] * W3[i * 8 + j];
      tt[i] = s;
    }
    B0[g] = tt[0]; B1[g] = tt[1]; B2[g] = tt[2];
    S3hat[g] = d * tt[3];
  }
}

__global__ void k_gp1_bu(const int* __restrict__ rowptr, const int2* __restrict__ adj,
                         const float* __restrict__ uin, const float* __restrict__ B,
                         const float* __restrict__ dis, float* __restrict__ uout, int N) {
  int g = (blockIdx.x * blockDim.x + threadIdx.x) / GPN;
  int l = threadIdx.x & (GPN - 1);
  if (g >= N) return;
  float acc = edge_sum1(adj, uin, rowptr[g], rowptr[g + 1], l);
  if (l == 0) {
    float d = dis[g];
    uout[g] = d * (B[g] + d * acc);
  }
}

__global__ void k_gp1_last(const int* __restrict__ rowptr, const int2* __restrict__ adj,
                           const float* __restrict__ uin, const float* __restrict__ B0,
                           const float* __restrict__ b3, const float* __restrict__ dis,
                           float* __restrict__ r, unsigned* __restrict__ keys,
                           double* __restrict__ partials, int N) {
  __shared__ double s1[BS];
  __shared__ double s2[BS];
  int tid = blockIdx.x * blockDim.x + threadIdx.x;
  int g = tid / GPN, l = tid & (GPN - 1);
  float rv = 0.0f;
  bool writer = false;
  if (g < N) {
    float acc = edge_sum1(adj, uin, rowptr[g], rowptr[g + 1], l);
    if (l == 0) {
      float gg = B0[g] + dis[g] * acc;
      rv = relu_(gg + b3[0]);
      r[g] = rv;
      keys[g] = __float_as_uint(rv) | 0x80000000u;
      writer = true;
    }
  }
  double v = writer ? (double)rv : 0.0;
  s1[threadIdx.x] = v;
  s2[threadIdx.x] = v * v;
  __syncthreads();
  for (int off = 128; off; off >>= 1) {
    if (threadIdx.x < off) {
      s1[threadIdx.x] += s1[threadIdx.x + off];
      s2[threadIdx.x] += s2[threadIdx.x + off];
    }
    __syncthreads();
  }
  if (threadIdx.x == 0) {
    partials[2 * (size_t)blockIdx.x]     = s1[0];
    partials[2 * (size_t)blockIdx.x + 1] = s2[0];
  }
}

// stats + topk-state init (fused)
__global__ void k_stats(const double* __restrict__ partials, int nparts,
                        float* __restrict__ stats, unsigned* __restrict__ state,
                        const int* __restrict__ kp, int N) {
  __shared__ double s1[BS];
  __shared__ double s2[BS];
  int t = threadIdx.x;
  double a = 0.0, b = 0.0;
  for (int i = t; i < nparts; i += BS) { a += partials[2 * (size_t)i]; b += partials[2 * (size_t)i + 1]; }
  s1[t] = a; s2[t] = b;
  __syncthreads();
  for (int off = 128; off; off >>= 1) {
    if (t < off) { s1[t] += s1[t + off]; s2[t] += s2[t + off]; }
    __syncthreads();
  }
  if (t == 0) {
    double mean = s1[0] / (double)N;
    double var  = s2[0] / (double)N - mean * mean;
    stats[0] = (float)mean;
    stats[1] = (float)(1.0 / sqrt(var + 1e-5));
    state[0] = 0u;
    state[1] = (unsigned)kp[0];
  }
}

// ======================= top-k: multi-block radix select (r7-proven) =======================

__global__ void k_hist(const unsigned* __restrict__ keys, int N,
                       const unsigned* __restrict__ state, unsigned* __restrict__ hist,
                       int shift) {
  __shared__ unsigned sh[256];
  sh[threadIdx.x] = 0;
  __syncthreads();
  unsigned prefix = state[0];
  unsigned hmask = (shift >= 24) ? 0u : (0xFFFFFFFFu << (shift + 8));
  int stride = gridDim.x * blockDim.x;
  for (int n = blockIdx.x * blockDim.x + threadIdx.x; n < N; n += stride) {
    unsigned kk = keys[n];
    if ((kk & hmask) == (prefix & hmask)) atomicAdd(&sh[(kk >> shift) & 255u], 1u);
  }
  __syncthreads();
  atomicAdd(&hist[threadIdx.x], sh[threadIdx.x]);
}

__global__ void k_select(unsigned* __restrict__ state, unsigned* __restrict__ hist, int shift) {
  __shared__ unsigned sh[BS];
  int t = threadIdx.x;
  unsigned c = hist[t];
  sh[t] = c;
  __syncthreads();
  for (int off = 1; off < BS; off <<= 1) {
    unsigned add = (t + off < BS) ? sh[t + off] : 0u; __syncthreads();
    sh[t] += add; __syncthreads();
  }
  unsigned rem = state[1];
  unsigned S = sh[t];
  if (S >= rem && (S - c) < rem) {
    state[0] |= ((unsigned)t) << shift;
    state[1] = rem - (S - c);
  }
  hist[t] = 0;
}

__global__ void k_mark(const unsigned* __restrict__ keys, const float* __restrict__ r,
                       const float* __restrict__ stats, int N,
                       const unsigned* __restrict__ state, float* __restrict__ out,
                       unsigned* __restrict__ blkcnt) {
  unsigned T = state[0];
  float mean = stats[0], istd = stats[1];
  int n = blockIdx.x * 256 + threadIdx.x;
  int eq = 0;
  __shared__ int sh;
  if (threadIdx.x == 0) sh = 0;
  __syncthreads();
  if (n < N) {
    out[2 * (size_t)n] = (r[n] - mean) * istd;
    unsigned kk = keys[n];
    out[2 * (size_t)n + 1] = (kk > T) ? 1.0f : 0.0f;
    eq = (kk == T);
  }
  if (eq) atomicAdd(&sh, 1);
  __syncthreads();
  if (threadIdx.x == 0) blkcnt[blockIdx.x] = (unsigned)sh;
}

__global__ void k_scanP(const unsigned* __restrict__ blkcnt, unsigned* __restrict__ scanbuf, int NB) {
  __shared__ unsigned sh[BS];
  int t = threadIdx.x;
  unsigned c0 = (2 * t < NB) ? blkcnt[2 * t] : 0u;
  unsigned c1 = (2 * t + 1 < NB) ? blkcnt[2 * t + 1] : 0u;
  unsigned s = c0 + c1;
  sh[t] = s; __syncthreads();
  for (int off = 1; off < BS; off <<= 1) {
    unsigned add = (t >= off) ? sh[t - off] : 0u; __syncthreads();
    sh[t] += add; __syncthreads();
  }
  unsigned ex = sh[t] - s;
  if (2 * t < NB) scanbuf[2 * t] = ex;
  if (2 * t + 1 < NB) scanbuf[2 * t + 1] = ex + c0;
}

__global__ void k_resolve(const unsigned* __restrict__ keys, int N,
                          const unsigned* __restrict__ state,
                          const unsigned* __restrict__ scanbuf, float* __restrict__ out) {
  unsigned T = state[0];
  unsigned m = state[1];
  int n = blockIdx.x * 256 + threadIdx.x;
  if (n >= N) return;
  if (keys[n] != T) return;
  unsigned rank = scanbuf[blockIdx.x];
  int base = blockIdx.x * 256;
  for (int j = base; j < n; ++j) rank += (keys[j] == T);
  out[2 * (size_t)n + 1] = (rank < m) ? 1.0f : 0.0f;
}

// ======================= launcher =======================

extern "C" void kernel_launch(void* const* d_in, const int* in_sizes, int n_in,
                              void* d_out, int out_size, void* d_ws, size_t ws_size,
                              hipStream_t stream) {
  const float* x    = (const float*)d_in[0];
  const int*   ei   = (const int*)d_in[1];
  const float* attr = (const float*)d_in[2];
  const int*   kp   = (const int*)d_in[3];
  const float* W1   = (const float*)d_in[4];
  const float* b1   = (const float*)d_in[5];
  const float* W2   = (const float*)d_in[6];
  const float* b2   = (const float*)d_in[7];
  const float* W3   = (const float*)d_in[8];
  const float* b3   = (const float*)d_in[9];
  const int N = in_sizes[0];
  const int E = in_sizes[2];
  const int* src = ei;
  const int* dst = ei + E;
  float* out = (float*)d_out;
  const int NB    = (N + 255) / 256;
  const int NB2   = (N + 1023) / 1024;
  const int NBUCK = (N + NPB - 1) >> BSH;
  const int chunk = (E + NBLKB - 1) / NBLKB;
  const int GGB   = (int)(((size_t)N * GPN + BS - 1) / BS);

  // ---- bump allocator over d_ws ----
  char* p = (char*)d_ws;
  auto alloc = [&](size_t bytes) -> char* {
    char* r = p; p += (bytes + 255) & ~(size_t)255; return r;
  };
  float*    dis    = (float*)alloc((size_t)N * 4);
  float*    xhat   = (float*)alloc((size_t)N * 4);
  float*    h1     = (float*)alloc((size_t)N * 4);
  float*    h2     = (float*)alloc((size_t)N * 4);
  float*    u1     = (float*)alloc((size_t)N * 4);
  float*    u2     = (float*)alloc((size_t)N * 4);
  float*    y      = (float*)alloc((size_t)N * 32);
  float*    Phat   = (float*)alloc((size_t)N * 32);
  float*    Qhat   = (float*)alloc((size_t)N * 32);
  float*    S3hat  = (float*)alloc((size_t)N * 4);
  float*    B2     = (float*)alloc((size_t)N * 4);
  float*    B1     = (float*)alloc((size_t)N * 4);
  float*    B0     = (float*)alloc((size_t)N * 4);
  float*    g2hat  = (float*)alloc((size_t)N * 4);
  float*    g1hat  = (float*)alloc((size_t)N * 4);
  float*    r      = (float*)alloc((size_t)N * 4);
  unsigned* keys   = (unsigned*)alloc((size_t)N * 4);
  double*   parts  = (double*)alloc((size_t)GGB * 16);
  float*    stats  = (float*)alloc(8);
  unsigned* state  = (unsigned*)alloc(8);
  unsigned* hist   = (unsigned*)alloc(1024);
  unsigned* blkcnt = (unsigned*)alloc((size_t)NB * 4);
  unsigned* scanbf = (unsigned*)alloc((size_t)NB * 4);
  int*      rowptr = (int*)alloc((size_t)(N + 1) * 4);
  int*      cursor = (int*)alloc((size_t)N * 4);
  int*      cnt    = (int*)alloc((size_t)N * 4);
  int*      bsum   = (int*)alloc(2048);
  int2*     adj    = (int2*)alloc((size_t)E * 8);
  int2*     bed    = (int2*)alloc((size_t)E * 8);
  int*      bcnt   = (int*)alloc((size_t)NBUCK * NBLKB * 4);
  int*      btot   = (int*)alloc((size_t)NBUCK * 4 + 256);
  int*      bbase  = (int*)alloc((size_t)NBUCK * 4 + 256);
  size_t need_new = (size_t)(p - (char*)d_ws);

  dim3 B(BS);
  int genb = (E + BS - 1) / BS;
  dim3 GE(genb), GG(GGB), GN(NB), GB(NBUCK);

  bool use_new = (need_new <= ws_size) && (N <= 102400) && (NBUCK <= SMAX);

  hipMemsetAsync(hist, 0, 1024, stream);

  if (use_new) {
    // bucketed bed build + bucket-streaming props (no CSR, no adj)
    k_binhist<<<dim3(NBLKB), dim3(BSB), 0, stream>>>(dst, bcnt, E, chunk, NBUCK);
    k_bucketscan<<<GB, B, 0, stream>>>(bcnt, btot);
    k_basescan<<<dim3(1), B, 0, stream>>>(btot, bbase, NBUCK);
    k_bin<<<dim3(NBLKB), dim3(BSB), 0, stream>>>(src, dst, attr, bcnt, bbase, bed, E, chunk, NBUCK);
    kb_degdis<<<GB, dim3(BSF), 0, stream>>>(bed, bbase, btot, x, dis, xhat, N);

    // layer 1
    kb_gp1_uh<<<GB, dim3(BSF), 0, stream>>>(bed, bbase, btot, xhat, dis, h1, u1, N);
    kb_gp1_uh<<<GB, dim3(BSF), 0, stream>>>(bed, bbase, btot, u1, dis, h2, u2, N);
    kb_gp1_y<<<GB, dim3(BSF), 0, stream>>>(bed, bbase, btot, u2, x, h1, h2, dis, W1, b1, W2 + 3 * 64, y, Phat, N);
    // layer 2
    kb_gp8_u<<<GB, dim3(BSF), 0, stream>>>(bed, bbase, btot, Phat, y, W2 + 2 * 64, dis, Qhat, N);
    kb_gp8_u<<<GB, dim3(BSF), 0, stream>>>(bed, bbase, btot, Qhat, y, W2 + 1 * 64, dis, Phat, N);
    kb_gp8_fin<<<GB, dim3(BSF), 0, stream>>>(bed, bbase, btot, Phat, y, W2, b2, W3, dis, S3hat, B2, B1, B0, N);
    // layer 3
    kb_gp1_bu<<<GB, dim3(BSF), 0, stream>>>(bed, bbase, btot, S3hat, B2, dis, g2hat, N);
    kb_gp1_bu<<<GB, dim3(BSF), 0, stream>>>(bed, bbase, btot, g2hat, B1, dis, g1hat, N);
    kb_gp1_last<<<GB, dim3(BSF), 0, stream>>>(bed, bbase, btot, g1hat, B0, b3, dis, r, keys, parts, N);

    k_stats<<<dim3(1), B, 0, stream>>>(parts, NBUCK, stats, state, kp, N);
  } else {
    // fallback: global-atomic CSR build + gather props
    hipMemsetAsync(cnt, 0, (size_t)N * 4, stream);
    k_count<<<GE, B, 0, stream>>>(dst, cnt, E);
    k_scanA<<<dim3(NB2), B, 0, stream>>>(cnt, bsum, N);
    k_scanB<<<dim3(1), B, 0, stream>>>(bsum, NB2);
    k_scanC<<<dim3(NB2), B, 0, stream>>>(cnt, bsum, rowptr, cursor, N, E);
    k_place<<<GE, B, 0, stream>>>(src, dst, attr, cursor, adj, E);
    k_degdis<<<GG, B, 0, stream>>>(rowptr, adj, x, dis, xhat, N);

    k_gp1_uh<<<GG, B, 0, stream>>>(rowptr, adj, xhat, dis, h1, u1, N);
    k_gp1_uh<<<GG, B, 0, stream>>>(rowptr, adj, u1, dis, h2, u2, N);
    k_gp1_y<<<GG, B, 0, stream>>>(rowptr, adj, u2, x, h1, h2, dis, W1, b1, W2 + 3 * 64, y, Phat, N);
    k_gp8_u<<<GG, B, 0, stream>>>(rowptr, adj, Phat, y, W2 + 2 * 64, dis, Qhat, N);
    k_gp8_u<<<GG, B, 0, stream>>>(rowptr, adj, Qhat, y, W2 + 1 * 64, dis, Phat, N);
    k_gp8_fin<<<GG, B, 0, stream>>>(rowptr, adj, Phat, y, W2, b2, W3, dis, S3hat, B2, B1, B0, N);
    k_gp1_bu<<<GG, B, 0, stream>>>(rowptr, adj, S3hat, B2, dis, g2hat, N);
    k_gp1_bu<<<GG, B, 0, stream>>>(rowptr, adj, g2hat, B1, dis, g1hat, N);
    k_gp1_last<<<GG, B, 0, stream>>>(rowptr, adj, g1hat, B0, b3, dis, r, keys, parts, N);

    k_stats<<<dim3(1), B, 0, stream>>>(parts, GGB, stats, state, kp, N);
  }

  // top-k: multi-block 4-round radix select (order invariant under affine normalize)
  for (int shift = 24; shift >= 0; shift -= 8) {
    k_hist<<<GN, B, 0, stream>>>(keys, N, state, hist, shift);
    k_select<<<dim3(1), B, 0, stream>>>(state, hist, shift);
  }
  k_mark<<<GN, B, 0, stream>>>(keys, r, stats, N, state, out, blkcnt);
  k_scanP<<<dim3(1), B, 0, stream>>>(blkcnt, scanbf, NB);
  k_resolve<<<GN, B, 0, stream>>>(keys, N, state, scanbf, out);
}

// Round 14
// 531.481 us; speedup vs baseline: 2.7475x; 2.7475x over previous
//
#include <hip/hip_runtime.h>

#define BS 256
#define BSB 512      // block size for binhist/bin
#define BSF 1024     // block size for cntfill
#define GPN 16       // lanes per node in gather props
#define NBLKB 1024   // blocks in binning pass (bucketscan VPT = NBLKB/256 = 4)
#define BSH 8        // nodes per bucket = 256
#define SMAX 400     // max buckets supported by staged k_bin (N <= 102400)

static __device__ __forceinline__ float relu_(float v) { return fmaxf(v, 0.0f); }

// ======================= bucketed CSR build (no global atomics) =======================

__global__ void k_binhist(const int* __restrict__ dst, int* __restrict__ bcnt,
                          int E, int chunk, int nbuck) {
  __shared__ int h[1024];
  int b = blockIdx.x, t = threadIdx.x;
  for (int i = t; i < nbuck; i += BSB) h[i] = 0;
  __syncthreads();
  int beg = b * chunk, end = min(E, beg + chunk);
  for (int e = beg + t; e < end; e += BSB) atomicAdd(&h[dst[e] >> BSH], 1);
  __syncthreads();
  for (int i = t; i < nbuck; i += BSB) bcnt[(size_t)i * NBLKB + b] = h[i];
}

// per bucket: exclusive scan of its NBLKB block counts (in place); total -> btot
__global__ void k_bucketscan(int* __restrict__ bcnt, int* __restrict__ btot) {
  __shared__ int sh[BS];
  int bkt = blockIdx.x, t = threadIdx.x;
  size_t base = (size_t)bkt * NBLKB;
  int c[4], s = 0;
#pragma unroll
  for (int j = 0; j < 4; ++j) { c[j] = bcnt[base + t * 4 + j]; s += c[j]; }
  sh[t] = s; __syncthreads();
  for (int off = 1; off < BS; off <<= 1) {
    int add = (t >= off) ? sh[t - off] : 0; __syncthreads();
    sh[t] += add; __syncthreads();
  }
  int run = sh[t] - s;
#pragma unroll
  for (int j = 0; j < 4; ++j) { bcnt[base + t * 4 + j] = run; run += c[j]; }
  if (t == BS - 1) btot[bkt] = run;
}

__global__ void k_basescan(const int* __restrict__ btot, int* __restrict__ bbase, int nbuck) {
  __shared__ int sh[BS];
  int t = threadIdx.x;
  int run = 0;
  for (int c = 0; c < nbuck; c += BS) {
    int i = c + t;
    int v = (i < nbuck) ? btot[i] : 0;
    sh[t] = v; __syncthreads();
    for (int off = 1; off < BS; off <<= 1) {
      int add = (t >= off) ? sh[t - off] : 0; __syncthreads();
      sh[t] += add; __syncthreads();
    }
    if (i < nbuck) bbase[i] = run + sh[t] - v;
    run += sh[BS - 1];
    __syncthreads();
  }
}

// bin edges into bucket-contiguous bed[] = {(d_local<<17)|src, |attr|}
// LDS cursors + per-bucket 64B line staging: global writes are full-line bursts.
__global__ void k_bin(const int* __restrict__ src, const int* __restrict__ dst,
                      const float* __restrict__ attr, const int* __restrict__ bcnt,
                      const int* __restrict__ bbase, int2* __restrict__ bed,
                      int E, int chunk, int nbuck) {
  __shared__ int2 stage[SMAX][8];
  __shared__ int  fc[SMAX];
  __shared__ int  cur[SMAX];
  int b = blockIdx.x, t = threadIdx.x;
  for (int i = t; i < nbuck; i += BSB) {
    cur[i] = bbase[i] + bcnt[(size_t)i * NBLKB + b];
    fc[i] = 0;
  }
  __syncthreads();
  int beg = b * chunk, end = min(E, beg + chunk);
  for (int base = beg; base < end; base += BSB) {
    int e = base + t;
    if (e < end) {
      int d = dst[e];
      int bkt = d >> BSH;
      int2 rec = make_int2((int)(((unsigned)(d & ((1 << BSH) - 1)) << 17) | (unsigned)src[e]),
                           __float_as_int(fabsf(attr[e])));
      int slot = atomicAdd(&fc[bkt], 1);
      if (slot < 8) stage[bkt][slot] = rec;
      else { int gp = atomicAdd(&cur[bkt], 1); bed[gp] = rec; }  // rare spill
    }
    __syncthreads();
    for (int i = t; i < nbuck; i += BSB) {
      int c = fc[i]; if (c > 8) c = 8;
      if (c == 8) {                       // flush one full 64B group
        int gp = cur[i]; cur[i] = gp + 8;
#pragma unroll
        for (int j = 0; j < 8; ++j) bed[gp + j] = stage[i][j];
        fc[i] = 0;
      }
    }
    __syncthreads();
  }
  for (int i = t; i < nbuck; i += BSB) {     // drain partial groups
    int c = fc[i]; if (c > 8) c = 8;
    if (c) {
      int gp = cur[i];
      for (int j = 0; j < c; ++j) bed[gp + j] = stage[i][j];
    }
  }
}

// per bucket (256 nodes, 1024 threads): count+deg+dis+xhat+rowptr (pass1),
// then scatter into CSR adj with 16-deep per-node line staging (pass2, bed hits L2).
__global__ void k_cntfill(const int2* __restrict__ bed, const int* __restrict__ bbase,
                          const int* __restrict__ btot, const float* __restrict__ x,
                          float* __restrict__ dis, float* __restrict__ xhat,
                          int* __restrict__ rowptr, int2* __restrict__ adj, int N, int E) {
  __shared__ int2  stage[1 << BSH][16];
  __shared__ int   lc[1 << BSH];
  __shared__ float ld[1 << BSH];
  __shared__ int   sc[1 << BSH];
  __shared__ int   fc[1 << BSH];
  __shared__ int   rcur[1 << BSH];
  int bkt = blockIdx.x, t = threadIdx.x;
  if (t < (1 << BSH)) { lc[t] = 0; ld[t] = 0.f; }
  __syncthreads();
  int beg = bbase[bkt], tot = btot[bkt];
  // pass 1: counts + degree
  for (int i = t; i < tot; i += BSF) {
    int2 rec = bed[beg + i];
    int dl = (int)((unsigned)rec.x >> 17);
    atomicAdd(&lc[dl], 1);
    atomicAdd(&ld[dl], __int_as_float(rec.y));
  }
  __syncthreads();
  if (t < (1 << BSH)) sc[t] = lc[t];
  __syncthreads();
  for (int off = 1; off < (1 << BSH); off <<= 1) {
    int add = 0;
    if (t < (1 << BSH) && t >= off) add = sc[t - off];
    __syncthreads();
    if (t < (1 << BSH)) sc[t] += add;
    __syncthreads();
  }
  if (t < (1 << BSH)) {
    int myrow = beg + sc[t] - lc[t];
    rcur[t] = myrow;
    fc[t] = 0;
    int n = (bkt << BSH) + t;
    if (n < N) {
      rowptr[n] = myrow;
      float dg = ld[t];
      float d = (dg > 0.f) ? (1.0f / sqrtf(dg)) : 0.f;
      dis[n] = d;
      xhat[n] = d * x[n];
    }
  }
  if (bkt == (int)gridDim.x - 1 && t == 0) rowptr[N] = E;
  __syncthreads();
  // pass 2: scatter (bed range ~128KB -> L2 hit)
  for (int base = 0; base < tot; base += BSF) {
    int i = base + t;
    if (i < tot) {
      int2 rec = bed[beg + i];
      unsigned u = (unsigned)rec.x;
      int dl = (int)(u >> 17);
      int2 orec = make_int2((int)(u & 0x1FFFFu), rec.y);
      int slot = atomicAdd(&fc[dl], 1);
      if (slot < 16) stage[dl][slot] = orec;
      else { int gp = atomicAdd(&rcur[dl], 1); adj[gp] = orec; }
    }
    __syncthreads();
    if (t < (1 << BSH)) {
      int c = fc[t]; if (c > 16) c = 16;
      if (c == 16) {
        int gp = rcur[t]; rcur[t] = gp + 16;
#pragma unroll
        for (int j = 0; j < 16; ++j) adj[gp + j] = stage[t][j];
        fc[t] = 0;
      }
    }
    __syncthreads();
  }
  if (t < (1 << BSH)) {
    int c = fc[t]; if (c > 16) c = 16;
    if (c) {
      int gp = rcur[t];
      for (int j = 0; j < c; ++j) adj[gp + j] = stage[t][j];
    }
  }
}

// ======================= fallback CSR build (global atomics) =======================

__global__ void k_scanA(const int* __restrict__ cnt, int* __restrict__ bsum, int N) {
  __shared__ int sh[BS];
  int t = threadIdx.x;
  int base = blockIdx.x * 1024;
  int s = 0;
#pragma unroll
  for (int j = 0; j < 4; ++j) { int i = base + t * 4 + j; s += (i < N) ? cnt[i] : 0; }
  sh[t] = s; __syncthreads();
  for (int off = 128; off; off >>= 1) { if (t < off) sh[t] += sh[t + off]; __syncthreads(); }
  if (t == 0) bsum[blockIdx.x] = sh[0];
}

__global__ void k_scanB(int* __restrict__ bsum, int NB2) {
  __shared__ int sh[BS];
  int t = threadIdx.x;
  int v = (t < NB2) ? bsum[t] : 0;
  sh[t] = v; __syncthreads();
  for (int off = 1; off < BS; off <<= 1) {
    int add = (t >= off) ? sh[t - off] : 0; __syncthreads();
    sh[t] += add; __syncthreads();
  }
  if (t < NB2) bsum[t] = sh[t] - v;
}

__global__ void k_scanC(const int* __restrict__ cnt, const int* __restrict__ bsum,
                        int* __restrict__ rowptr, int* __restrict__ cursor, int N, int E) {
  __shared__ int sh[BS];
  int b = blockIdx.x, t = threadIdx.x;
  int base = b * 1024;
  int c[4]; int s = 0;
#pragma unroll
  for (int j = 0; j < 4; ++j) { int i = base + t * 4 + j; c[j] = (i < N) ? cnt[i] : 0; s += c[j]; }
  sh[t] = s; __syncthreads();
  for (int off = 1; off < BS; off <<= 1) {
    int add = (t >= off) ? sh[t - off] : 0; __syncthreads();
    sh[t] += add; __syncthreads();
  }
  int run = sh[t] - s + bsum[b];
#pragma unroll
  for (int j = 0; j < 4; ++j) {
    int i = base + t * 4 + j;
    if (i < N) { rowptr[i] = run; if (cursor) cursor[i] = run; run += c[j]; }
  }
  if (b == 0 && t == 0) rowptr[N] = E;
}

__global__ void k_count(const int* __restrict__ dst, int* __restrict__ cnt, int E) {
  int e = blockIdx.x * blockDim.x + threadIdx.x;
  if (e < E) atomicAdd(&cnt[dst[e]], 1);
}

__global__ void k_place(const int* __restrict__ src, const int* __restrict__ dst,
                        const float* __restrict__ attr, int* __restrict__ cursor,
                        int2* __restrict__ adj, int E) {
  int e = blockIdx.x * blockDim.x + threadIdx.x;
  if (e >= E) return;
  int d = dst[e];
  int pos = atomicAdd(&cursor[d], 1);
  adj[pos] = make_int2(src[e], __float_as_int(fabsf(attr[e])));
}

__global__ void k_degdis(const int* __restrict__ rowptr, const int2* __restrict__ adj,
                         const float* __restrict__ x, float* __restrict__ dis,
                         float* __restrict__ xhat, int N) {
  int g = (blockIdx.x * blockDim.x + threadIdx.x) / GPN;
  int l = threadIdx.x & (GPN - 1);
  if (g >= N) return;
  int beg = rowptr[g], end = rowptr[g + 1];
  float s = 0.0f;
  for (int e = beg + l; e < end; e += GPN) s += __int_as_float(adj[e].y);
#pragma unroll
  for (int off = 8; off; off >>= 1) s += __shfl_xor(s, off, GPN);
  if (l == 0) {
    float d = (s > 0.0f) ? (1.0f / sqrtf(s)) : 0.0f;
    dis[g] = d;
    xhat[g] = d * x[g];
  }
}

// ======================= u-space gather props (unroll-2) =======================
// uhat = dis*h; per-edge weight stays raw |attr|; acc = sum w*uhat[src].

static __device__ __forceinline__ float edge_sum1(const int2* __restrict__ adj,
                                                  const float* __restrict__ uin,
                                                  int beg, int end, int l) {
  float acc0 = 0.0f, acc1 = 0.0f;
  int e = beg + l;
  int last = end - GPN;
  for (; e < last; e += 2 * GPN) {
    int2 s0 = adj[e], s1 = adj[e + GPN];
    acc0 += __int_as_float(s0.y) * uin[s0.x];
    acc1 += __int_as_float(s1.y) * uin[s1.x];
  }
  if (e < end) { int2 s0 = adj[e]; acc0 += __int_as_float(s0.y) * uin[s0.x]; }
  float acc = acc0 + acc1;
#pragma unroll
  for (int off = 8; off; off >>= 1) acc += __shfl_xor(acc, off, GPN);
  return acc;
}

__global__ void k_gp1_uh(const int* __restrict__ rowptr, const int2* __restrict__ adj,
                         const float* __restrict__ uin, const float* __restrict__ dis,
                         float* __restrict__ hout, float* __restrict__ uout, int N) {
  int g = (blockIdx.x * blockDim.x + threadIdx.x) / GPN;
  int l = threadIdx.x & (GPN - 1);
  if (g >= N) return;
  float acc = edge_sum1(adj, uin, rowptr[g], rowptr[g + 1], l);
  if (l == 0) {
    float d = dis[g];
    float h = d * acc;
    hout[g] = h;
    uout[g] = d * h;
  }
}

__global__ void k_gp1_y(const int* __restrict__ rowptr, const int2* __restrict__ adj,
                        const float* __restrict__ u2, const float* __restrict__ x,
                        const float* __restrict__ h1, const float* __restrict__ h2,
                        const float* __restrict__ dis, const float* __restrict__ W1,
                        const float* __restrict__ b1, const float* __restrict__ W23,
                        float* __restrict__ y, float* __restrict__ Phat, int N) {
  int g = (blockIdx.x * blockDim.x + threadIdx.x) / GPN;
  int l = threadIdx.x & (GPN - 1);
  if (g >= N) return;
  float acc = edge_sum1(adj, u2, rowptr[g], rowptr[g + 1], l);
  if (l == 0) {
    float d = dis[g];
    float xv = x[g], a = h1[g], b = h2[g], c = d * acc;
    float o[8];
#pragma unroll
    for (int j = 0; j < 8; ++j)
      o[j] = relu_(xv * W1[j] + a * W1[8 + j] + b * W1[16 + j] + c * W1[24 + j] + b1[j]);
    float4* op = (float4*)(y + (size_t)g * 8);
    op[0] = make_float4(o[0], o[1], o[2], o[3]);
    op[1] = make_float4(o[4], o[5], o[6], o[7]);
    float p[8];
#pragma unroll
    for (int j = 0; j < 8; ++j) {
      float s = 0.0f;
#pragma unroll
      for (int i = 0; i < 8; ++i) s += o[i] * W23[i * 8 + j];
      p[j] = d * s;
    }
    float4* pp = (float4*)(Phat + (size_t)g * 8);
    pp[0] = make_float4(p[0], p[1], p[2], p[3]);
    pp[1] = make_float4(p[4], p[5], p[6], p[7]);
  }
}

#define EDGE_SUM8(ADJ, UIN, BEG, END, L)                                        \
  float a0=0,a1=0,a2=0,a3=0,a4=0,a5=0,a6=0,a7=0;                                \
  {                                                                             \
    int e = (BEG) + (L);                                                        \
    int last = (END) - GPN;                                                     \
    for (; e < last; e += 2 * GPN) {                                            \
      int2 s0 = (ADJ)[e], s1 = (ADJ)[e + GPN];                                  \
      float w0 = __int_as_float(s0.y), w1 = __int_as_float(s1.y);               \
      const float4* p0 = (const float4*)((UIN) + (size_t)s0.x * 8);             \
      const float4* p1 = (const float4*)((UIN) + (size_t)s1.x * 8);             \
      float4 u0 = p0[0], v0 = p0[1], u1 = p1[0], v1 = p1[1];                    \
      a0 += w0*u0.x; a1 += w0*u0.y; a2 += w0*u0.z; a3 += w0*u0.w;               \
      a4 += w0*v0.x; a5 += w0*v0.y; a6 += w0*v0.z; a7 += w0*v0.w;               \
      a0 += w1*u1.x; a1 += w1*u1.y; a2 += w1*u1.z; a3 += w1*u1.w;               \
      a4 += w1*v1.x; a5 += w1*v1.y; a6 += w1*v1.z; a7 += w1*v1.w;               \
    }                                                                           \
    if (e < (END)) {                                                            \
      int2 s0 = (ADJ)[e];                                                       \
      float w0 = __int_as_float(s0.y);                                          \
      const float4* p0 = (const float4*)((UIN) + (size_t)s0.x * 8);             \
      float4 u0 = p0[0], v0 = p0[1];                                            \
      a0 += w0*u0.x; a1 += w0*u0.y; a2 += w0*u0.z; a3 += w0*u0.w;               \
      a4 += w0*v0.x; a5 += w0*v0.y; a6 += w0*v0.z; a7 += w0*v0.w;               \
    }                                                                           \
  }                                                                             \
  _Pragma("unroll")                                                             \
  for (int off = 8; off; off >>= 1) {                                           \
    a0 += __shfl_xor(a0, off, GPN); a1 += __shfl_xor(a1, off, GPN);             \
    a2 += __shfl_xor(a2, off, GPN); a3 += __shfl_xor(a3, off, GPN);             \
    a4 += __shfl_xor(a4, off, GPN); a5 += __shfl_xor(a5, off, GPN);             \
    a6 += __shfl_xor(a6, off, GPN); a7 += __shfl_xor(a7, off, GPN);             \
  }

__global__ void k_gp8_u(const int* __restrict__ rowptr, const int2* __restrict__ adj,
                        const float* __restrict__ uin, const float* __restrict__ y,
                        const float* __restrict__ W, const float* __restrict__ dis,
                        float* __restrict__ uout, int N) {
  int g = (blockIdx.x * blockDim.x + threadIdx.x) / GPN;
  int l = threadIdx.x & (GPN - 1);
  if (g >= N) return;
  int beg = rowptr[g], end = rowptr[g + 1];
  EDGE_SUM8(adj, uin, beg, end, l)
  if (l == 0) {
    float d = dis[g];
    const float4* yp = (const float4*)(y + (size_t)g * 8);
    float4 u = yp[0], v = yp[1];
    float yi[8] = {u.x, u.y, u.z, u.w, v.x, v.y, v.z, v.w};
    float acc[8] = {a0, a1, a2, a3, a4, a5, a6, a7};
    float o[8];
#pragma unroll
    for (int j = 0; j < 8; ++j) {
      float s = 0.0f;
#pragma unroll
      for (int i = 0; i < 8; ++i) s += yi[i] * W[i * 8 + j];
      o[j] = d * (s + d * acc[j]);
    }
    float4* op = (float4*)(uout + (size_t)g * 8);
    op[0] = make_float4(o[0], o[1], o[2], o[3]);
    op[1] = make_float4(o[4], o[5], o[6], o[7]);
  }
}

__global__ void k_gp8_fin(const int* __restrict__ rowptr, const int2* __restrict__ adj,
                          const float* __restrict__ uin, const float* __restrict__ y,
                          const float* __restrict__ W0, const float* __restrict__ b2,
                          const float* __restrict__ W3, const float* __restrict__ dis,
                          float* __restrict__ S3hat, float* __restrict__ B2,
                          float* __restrict__ B1, float* __restrict__ B0, int N) {
  int g = (blockIdx.x * blockDim.x + threadIdx.x) / GPN;
  int l = threadIdx.x & (GPN - 1);
  if (g >= N) return;
  int beg = rowptr[g], end = rowptr[g + 1];
  EDGE_SUM8(adj, uin, beg, end, l)
  if (l == 0) {
    float d = dis[g];
    const float4* yp = (const float4*)(y + (size_t)g * 8);
    float4 u = yp[0], v = yp[1];
    float yi[8] = {u.x, u.y, u.z, u.w, v.x, v.y, v.z, v.w};
    float acc[8] = {a0, a1, a2, a3, a4, a5, a6, a7};
    float z[8];
#pragma unroll
    for (int j = 0; j < 8; ++j) {
      float s = 0.0f;
#pragma unroll
      for (int i = 0; i < 8; ++i) s += yi[i] * W0[i * 8 + j];
      z[j] = relu_(s + d * acc[j] + b2[j]);
    }
    float tt[4];
#pragma unroll
    for (int i = 0; i < 4; ++i) {
      float s = 0.0f;
#pragma unroll
      for (int j = 0; j < 8; ++j) s += z[j] * W3[i * 8 + j];
      tt[i] = s;
    }
    B0[g] = tt[0]; B1[g] = tt[1]; B2[g] = tt[2];
    S3hat[g] = d * tt[3];
  }
}

__global__ void k_gp1_bu(const int* __restrict__ rowptr, const int2* __restrict__ adj,
                         const float* __restrict__ uin, const float* __restrict__ B,
                         const float* __restrict__ dis, float* __restrict__ uout, int N) {
  int g = (blockIdx.x * blockDim.x + threadIdx.x) / GPN;
  int l = threadIdx.x & (GPN - 1);
  if (g >= N) return;
  float acc = edge_sum1(adj, uin, rowptr[g], rowptr[g + 1], l);
  if (l == 0) {
    float d = dis[g];
    uout[g] = d * (B[g] + d * acc);
  }
}

__global__ void k_gp1_last(const int* __restrict__ rowptr, const int2* __restrict__ adj,
                           const float* __restrict__ uin, const float* __restrict__ B0,
                           const float* __restrict__ b3, const float* __restrict__ dis,
                           float* __restrict__ r, unsigned* __restrict__ keys,
                           double* __restrict__ partials, int N) {
  __shared__ double s1[BS];
  __shared__ double s2[BS];
  int tid = blockIdx.x * blockDim.x + threadIdx.x;
  int g = tid / GPN, l = tid & (GPN - 1);
  float rv = 0.0f;
  bool writer = false;
  if (g < N) {
    float acc = edge_sum1(adj, uin, rowptr[g], rowptr[g + 1], l);
    if (l == 0) {
      float gg = B0[g] + dis[g] * acc;
      rv = relu_(gg + b3[0]);
      r[g] = rv;
      keys[g] = __float_as_uint(rv) | 0x80000000u;  // rv >= 0
      writer = true;
    }
  }
  double v = writer ? (double)rv : 0.0;
  s1[threadIdx.x] = v;
  s2[threadIdx.x] = v * v;
  __syncthreads();
  for (int off = 128; off; off >>= 1) {
    if (threadIdx.x < off) {
      s1[threadIdx.x] += s1[threadIdx.x + off];
      s2[threadIdx.x] += s2[threadIdx.x + off];
    }
    __syncthreads();
  }
  if (threadIdx.x == 0) {
    partials[2 * (size_t)blockIdx.x]     = s1[0];
    partials[2 * (size_t)blockIdx.x + 1] = s2[0];
  }
}

__global__ void k_stats(const double* __restrict__ partials, int nparts,
                        float* __restrict__ stats, int N) {
  __shared__ double s1[BS];
  __shared__ double s2[BS];
  int t = threadIdx.x;
  double a = 0.0, b = 0.0;
  for (int i = t; i < nparts; i += BS) { a += partials[2 * (size_t)i]; b += partials[2 * (size_t)i + 1]; }
  s1[t] = a; s2[t] = b;
  __syncthreads();
  for (int off = 128; off; off >>= 1) {
    if (t < off) { s1[t] += s1[t + off]; s2[t] += s2[t + off]; }
    __syncthreads();
  }
  if (t == 0) {
    double mean = s1[0] / (double)N;
    double var  = s2[0] / (double)N - mean * mean;
    stats[0] = (float)mean;
    stats[1] = (float)(1.0 / sqrt(var + 1e-5));
  }
}

// ======================= top-k: multi-block radix select =======================

__global__ void k_stateinit(unsigned* __restrict__ state, const int* __restrict__ kp) {
  state[0] = 0u;
  state[1] = (unsigned)kp[0];
}

__global__ void k_hist(const unsigned* __restrict__ keys, int N,
                       const unsigned* __restrict__ state, unsigned* __restrict__ hist,
                       int shift) {
  __shared__ unsigned sh[256];
  sh[threadIdx.x] = 0;
  __syncthreads();
  unsigned prefix = state[0];
  unsigned hmask = (shift >= 24) ? 0u : (0xFFFFFFFFu << (shift + 8));
  int stride = gridDim.x * blockDim.x;
  for (int n = blockIdx.x * blockDim.x + threadIdx.x; n < N; n += stride) {
    unsigned kk = keys[n];
    if ((kk & hmask) == (prefix & hmask)) atomicAdd(&sh[(kk >> shift) & 255u], 1u);
  }
  __syncthreads();
  atomicAdd(&hist[threadIdx.x], sh[threadIdx.x]);
}

__global__ void k_select(unsigned* __restrict__ state, unsigned* __restrict__ hist, int shift) {
  __shared__ unsigned sh[BS];
  int t = threadIdx.x;
  unsigned c = hist[t];
  sh[t] = c;
  __syncthreads();
  for (int off = 1; off < BS; off <<= 1) {
    unsigned add = (t + off < BS) ? sh[t + off] : 0u; __syncthreads();
    sh[t] += add; __syncthreads();
  }
  unsigned rem = state[1];
  unsigned S = sh[t];
  if (S >= rem && (S - c) < rem) {
    state[0] |= ((unsigned)t) << shift;
    state[1] = rem - (S - c);
  }
  hist[t] = 0;
}

__global__ void k_mark(const unsigned* __restrict__ keys, const float* __restrict__ r,
                       const float* __restrict__ stats, int N,
                       const unsigned* __restrict__ state, float* __restrict__ out,
                       unsigned* __restrict__ blkcnt) {
  unsigned T = state[0];
  float mean = stats[0], istd = stats[1];
  int n = blockIdx.x * 256 + threadIdx.x;
  int eq = 0;
  __shared__ int sh;
  if (threadIdx.x == 0) sh = 0;
  __syncthreads();
  if (n < N) {
    out[2 * (size_t)n] = (r[n] - mean) * istd;
    unsigned kk = keys[n];
    out[2 * (size_t)n + 1] = (kk > T) ? 1.0f : 0.0f;
    eq = (kk == T);
  }
  if (eq) atomicAdd(&sh, 1);
  __syncthreads();
  if (threadIdx.x == 0) blkcnt[blockIdx.x] = (unsigned)sh;
}

__global__ void k_scanP(const unsigned* __restrict__ blkcnt, unsigned* __restrict__ scanbuf, int NB) {
  __shared__ unsigned sh[BS];
  int t = threadIdx.x;
  unsigned c0 = (2 * t < NB) ? blkcnt[2 * t] : 0u;
  unsigned c1 = (2 * t + 1 < NB) ? blkcnt[2 * t + 1] : 0u;
  unsigned s = c0 + c1;
  sh[t] = s; __syncthreads();
  for (int off = 1; off < BS; off <<= 1) {
    unsigned add = (t >= off) ? sh[t - off] : 0u; __syncthreads();
    sh[t] += add; __syncthreads();
  }
  unsigned ex = sh[t] - s;
  if (2 * t < NB) scanbuf[2 * t] = ex;
  if (2 * t + 1 < NB) scanbuf[2 * t + 1] = ex + c0;
}

__global__ void k_resolve(const unsigned* __restrict__ keys, int N,
                          const unsigned* __restrict__ state,
                          const unsigned* __restrict__ scanbuf, float* __restrict__ out) {
  unsigned T = state[0];
  unsigned m = state[1];
  int n = blockIdx.x * 256 + threadIdx.x;
  if (n >= N) return;
  if (keys[n] != T) return;
  unsigned rank = scanbuf[blockIdx.x];
  int base = blockIdx.x * 256;
  for (int j = base; j < n; ++j) rank += (keys[j] == T);
  out[2 * (size_t)n + 1] = (rank < m) ? 1.0f : 0.0f;
}

// ======================= launcher =======================

extern "C" void kernel_launch(void* const* d_in, const int* in_sizes, int n_in,
                              void* d_out, int out_size, void* d_ws, size_t ws_size,
                              hipStream_t stream) {
  const float* x    = (const float*)d_in[0];
  const int*   ei   = (const int*)d_in[1];
  const float* attr = (const float*)d_in[2];
  const int*   kp   = (const int*)d_in[3];
  const float* W1   = (const float*)d_in[4];
  const float* b1   = (const float*)d_in[5];
  const float* W2   = (const float*)d_in[6];
  const float* b2   = (const float*)d_in[7];
  const float* W3   = (const float*)d_in[8];
  const float* b3   = (const float*)d_in[9];
  const int N = in_sizes[0];
  const int E = in_sizes[2];
  const int* src = ei;
  const int* dst = ei + E;
  float* out = (float*)d_out;
  const int NB    = (N + 255) / 256;
  const int NB2   = (N + 1023) / 1024;
  const int NBUCK = (N + (1 << BSH) - 1) >> BSH;
  const int chunk = (E + NBLKB - 1) / NBLKB;
  const int GGB   = (int)(((size_t)N * GPN + BS - 1) / BS);   // gather-prop blocks

  // ---- bump allocator over d_ws ----
  char* p = (char*)d_ws;
  auto alloc = [&](size_t bytes) -> char* {
    char* r = p; p += (bytes + 255) & ~(size_t)255; return r;
  };
  float*    dis    = (float*)alloc((size_t)N * 4);
  float*    xhat   = (float*)alloc((size_t)N * 4);
  float*    h1     = (float*)alloc((size_t)N * 4);
  float*    h2     = (float*)alloc((size_t)N * 4);
  float*    u1     = (float*)alloc((size_t)N * 4);
  float*    u2     = (float*)alloc((size_t)N * 4);
  float*    y      = (float*)alloc((size_t)N * 32);
  float*    Phat   = (float*)alloc((size_t)N * 32);
  float*    Qhat   = (float*)alloc((size_t)N * 32);
  float*    S3hat  = (float*)alloc((size_t)N * 4);
  float*    B2     = (float*)alloc((size_t)N * 4);
  float*    B1     = (float*)alloc((size_t)N * 4);
  float*    B0     = (float*)alloc((size_t)N * 4);
  float*    g2hat  = (float*)alloc((size_t)N * 4);
  float*    g1hat  = (float*)alloc((size_t)N * 4);
  float*    r      = (float*)alloc((size_t)N * 4);
  unsigned* keys   = (unsigned*)alloc((size_t)N * 4);
  double*   parts  = (double*)alloc((size_t)GGB * 16);
  float*    stats  = (float*)alloc(8);
  unsigned* state  = (unsigned*)alloc(8);
  unsigned* hist   = (unsigned*)alloc(1024);
  unsigned* blkcnt = (unsigned*)alloc((size_t)NB * 4);
  unsigned* scanbf = (unsigned*)alloc((size_t)NB * 4);
  int*      rowptr = (int*)alloc((size_t)(N + 1) * 4);
  int*      cursor = (int*)alloc((size_t)N * 4);
  int*      cnt    = (int*)alloc((size_t)N * 4);
  int*      bsum   = (int*)alloc(2048);
  int2*     adj    = (int2*)alloc((size_t)E * 8);
  int2*     bed    = (int2*)alloc((size_t)E * 8);
  int*      bcnt   = (int*)alloc((size_t)NBUCK * NBLKB * 4);
  int*      btot   = (int*)alloc((size_t)NBUCK * 4 + 256);
  int*      bbase  = (int*)alloc((size_t)NBUCK * 4 + 256);
  size_t need_new = (size_t)(p - (char*)d_ws);

  dim3 B(BS);
  int genb = (E + BS - 1) / BS;
  dim3 GE(genb), GG(GGB), GN(NB), GB(NBUCK);

  bool use_new = (need_new <= ws_size) && (N <= 102400) && (NBUCK <= SMAX);

  hipMemsetAsync(hist, 0, 1024, stream);

  if (use_new) {
    // bucketed build: no global atomics, staged line writes
    k_binhist<<<dim3(NBLKB), dim3(BSB), 0, stream>>>(dst, bcnt, E, chunk, NBUCK);
    k_bucketscan<<<GB, B, 0, stream>>>(bcnt, btot);
    k_basescan<<<dim3(1), B, 0, stream>>>(btot, bbase, NBUCK);
    k_bin<<<dim3(NBLKB), dim3(BSB), 0, stream>>>(src, dst, attr, bcnt, bbase, bed, E, chunk, NBUCK);
    k_cntfill<<<GB, dim3(BSF), 0, stream>>>(bed, bbase, btot, x, dis, xhat, rowptr, adj, N, E);
  } else {
    // fallback: global-atomic CSR build (raw weights)
    hipMemsetAsync(cnt, 0, (size_t)N * 4, stream);
    k_count<<<GE, B, 0, stream>>>(dst, cnt, E);
    k_scanA<<<dim3(NB2), B, 0, stream>>>(cnt, bsum, N);
    k_scanB<<<dim3(1), B, 0, stream>>>(bsum, NB2);
    k_scanC<<<dim3(NB2), B, 0, stream>>>(cnt, bsum, rowptr, cursor, N, E);
    k_place<<<GE, B, 0, stream>>>(src, dst, attr, cursor, adj, E);
    k_degdis<<<GG, B, 0, stream>>>(rowptr, adj, x, dis, xhat, N);
  }

  // layer 1 (u-space scalar props; y + Phat fused into last)
  k_gp1_uh<<<GG, B, 0, stream>>>(rowptr, adj, xhat, dis, h1, u1, N);
  k_gp1_uh<<<GG, B, 0, stream>>>(rowptr, adj, u1, dis, h2, u2, N);
  k_gp1_y<<<GG, B, 0, stream>>>(rowptr, adj, u2, x, h1, h2, dis, W1, b1, W2 + 3 * 64, y, Phat, N);

  // layer 2 (u-space 8-dim Horner; bases fused; layer-3 projections fused into fin)
  k_gp8_u<<<GG, B, 0, stream>>>(rowptr, adj, Phat, y, W2 + 2 * 64, dis, Qhat, N);
  k_gp8_u<<<GG, B, 0, stream>>>(rowptr, adj, Qhat, y, W2 + 1 * 64, dis, Phat, N);
  k_gp8_fin<<<GG, B, 0, stream>>>(rowptr, adj, Phat, y, W2, b2, W3, dis, S3hat, B2, B1, B0, N);

  // layer 3 (u-space scalar Horner; final prop fused with relu/keys/stats partials)
  k_gp1_bu<<<GG, B, 0, stream>>>(rowptr, adj, S3hat, B2, dis, g2hat, N);
  k_gp1_bu<<<GG, B, 0, stream>>>(rowptr, adj, g2hat, B1, dis, g1hat, N);
  k_gp1_last<<<GG, B, 0, stream>>>(rowptr, adj, g1hat, B0, b3, dis, r, keys, parts, N);

  // stats (single pass over block partials)
  k_stats<<<dim3(1), B, 0, stream>>>(parts, GGB, stats, N);

  // top-k radix select on r-keys (order invariant under affine normalize)
  k_stateinit<<<dim3(1), dim3(1), 0, stream>>>(state, kp);
  for (int shift = 24; shift >= 0; shift -= 8) {
    k_hist<<<GN, B, 0, stream>>>(keys, N, state, hist, shift);
    k_select<<<dim3(1), B, 0, stream>>>(state, hist, shift);
  }
  k_mark<<<GN, B, 0, stream>>>(keys, r, stats, N, state, out, blkcnt);
  k_scanP<<<dim3(1), B, 0, stream>>>(blkcnt, scanbf, NB);
  k_resolve<<<GN, B, 0, stream>>>(keys, N, state, scanbf, out);
}